// Round 6
// baseline (156.683 us; speedup 1.0000x reference)
//
#include <hip/hip_runtime.h>

#define EPS 1.1920928955078125e-07f

// Problem constants
#define BB 32
#define TT 256000
#define T4 (TT / 4)                  // 64000 float4 per signal
#define CHUNKS 125                   // chunks per batch element
#define CHUNK 512                    // float4 per stream per block (64000/125)
#define NBLK (BB * CHUNKS)           // 4000 blocks
#define STAGE_INSTR (CHUNK / 64)     // 8 global_load_lds_dwordx4 per wave

// 12 per-batch statistics (raw sums; zero-meaning folded in at finalize):
// [0] sum p0   [1] sum p1   [2] sum t0   [3] sum t1
// [4] sum p0^2 [5] sum p1^2 [6] sum t0^2 [7] sum t1^2
// [8] sum p0*t0 [9] sum p0*t1 [10] sum p1*t0 [11] sum p1*t1

__global__ __launch_bounds__(256) void pit_partials(
    const float* __restrict__ preds, const float* __restrict__ targets,
    float* __restrict__ ws)
{
    // 4 streams x 512 float4 = 32 KB; also reused (post-barrier) as reduce buf
    __shared__ float4 tile[4][CHUNK];

    const int b    = blockIdx.x / CHUNKS;
    const int c    = blockIdx.x % CHUNKS;
    const int lane = threadIdx.x & 63;
    const int wave = threadIdx.x >> 6;

    // stream w base pointer: w=0,1 -> preds rows; w=2,3 -> targets rows
    const float* gbase = (wave < 2)
        ? preds   + (size_t)(b * 2 + (wave & 1)) * TT
        : targets + (size_t)(b * 2 + (wave & 1)) * TT;
    const float4* src = (const float4*)gbase + (size_t)c * CHUNK;

    // ---- stage: wave w copies stream w's 8 KB chunk into LDS as 8 sequential
    // fire-and-forget 1KB DMA bursts (no VGPR round-trip, depth can't be folded)
#pragma unroll
    for (int j = 0; j < STAGE_INSTR; ++j) {
        __builtin_amdgcn_global_load_lds(
            (const __attribute__((address_space(1))) void*)(src + j * 64 + lane),
            (__attribute__((address_space(3))) void*)&tile[wave][j * 64],
            16, 0, 0);
    }
    __syncthreads();   // drains vmcnt; other resident blocks compute meanwhile

    // ---- compute from LDS: 2 float4 per thread per stream
    float acc[12];
#pragma unroll
    for (int k = 0; k < 12; ++k) acc[k] = 0.f;

#pragma unroll
    for (int it = 0; it < CHUNK / 256; ++it) {
        const int i = (int)threadIdx.x + it * 256;
        float4 a0 = tile[0][i];
        float4 a1 = tile[1][i];
        float4 b0 = tile[2][i];
        float4 b1 = tile[3][i];
#pragma unroll
        for (int e = 0; e < 4; ++e) {
            float u0 = (&a0.x)[e], u1 = (&a1.x)[e];
            float v0 = (&b0.x)[e], v1 = (&b1.x)[e];
            acc[0]  += u0;       acc[1]  += u1;
            acc[2]  += v0;       acc[3]  += v1;
            acc[4]  += u0 * u0;  acc[5]  += u1 * u1;
            acc[6]  += v0 * v0;  acc[7]  += v1 * v1;
            acc[8]  += u0 * v0;  acc[9]  += u0 * v1;
            acc[10] += u1 * v0;  acc[11] += u1 * v1;
        }
    }

    // wave(64)-level shuffle reduction for all 12 stats
#pragma unroll
    for (int k = 0; k < 12; ++k) {
        float v = acc[k];
        for (int off = 32; off > 0; off >>= 1) v += __shfl_down(v, off);
        acc[k] = v;   // valid in lane 0 of each wave
    }

    __syncthreads();                   // tile reads done -> safe to reuse LDS
    float* red = (float*)tile;         // 4 waves x 12 stats
    if (lane == 0) {
#pragma unroll
        for (int k = 0; k < 12; ++k) red[wave * 12 + k] = acc[k];
    }
    __syncthreads();

    if (threadIdx.x < 12) {
        float v = red[0 * 12 + threadIdx.x] + red[1 * 12 + threadIdx.x]
                + red[2 * 12 + threadIdx.x] + red[3 * 12 + threadIdx.x];
        ws[(size_t)blockIdx.x * 12 + threadIdx.x] = v;
    }
}

// Reduce NBLK x 12 partials -> B x 12 stats -> SI-SNR -> PIT -> scalar loss
__global__ __launch_bounds__(256) void pit_final(
    const float* __restrict__ ws, float* __restrict__ out)
{
    __shared__ float sums[BB * 12];
    __shared__ float bests[BB];

    for (int s = threadIdx.x; s < BB * 12; s += 256) {
        const int b = s / 12;
        const int k = s % 12;
        float v = 0.f;
        const float* base = ws + (size_t)(b * CHUNKS) * 12 + k;
        for (int c = 0; c < CHUNKS; ++c) v += base[(size_t)c * 12];
        sums[s] = v;
    }
    __syncthreads();

    if (threadIdx.x < BB) {
        const float* w = sums + threadIdx.x * 12;
        const float invT = 1.0f / (float)TT;
        float pp0 = w[4] - w[0] * w[0] * invT;
        float pp1 = w[5] - w[1] * w[1] * invT;
        float tt0 = w[6] - w[2] * w[2] * invT;
        float tt1 = w[7] - w[3] * w[3] * invT;
        float d00 = w[8]  - w[0] * w[2] * invT;
        float d01 = w[9]  - w[0] * w[3] * invT;
        float d10 = w[10] - w[1] * w[2] * invT;
        float d11 = w[11] - w[1] * w[3] * invT;

        auto sisnr = [](float dot, float pp, float tt) -> float {
            float alpha = dot / (tt + EPS);
            float st    = alpha * alpha * tt;
            float noise = pp - 2.0f * alpha * dot + st;
            return 10.0f * log10f((st + EPS) / (noise + EPS));
        };
        float s00 = sisnr(d00, pp0, tt0);
        float s01 = sisnr(d01, pp0, tt1);
        float s10 = sisnr(d10, pp1, tt0);
        float s11 = sisnr(d11, pp1, tt1);

        float perm0 = 0.5f * (s00 + s11);
        float perm1 = 0.5f * (s01 + s10);
        bests[threadIdx.x] = fmaxf(perm0, perm1);
    }
    __syncthreads();

    if (threadIdx.x == 0) {
        float acc = 0.f;
#pragma unroll
        for (int b = 0; b < BB; ++b) acc += bests[b];
        out[0] = -acc / (float)BB;
    }
}

extern "C" void kernel_launch(void* const* d_in, const int* in_sizes, int n_in,
                              void* d_out, int out_size, void* d_ws, size_t ws_size,
                              hipStream_t stream)
{
    const float* preds   = (const float*)d_in[0];
    const float* targets = (const float*)d_in[1];
    float* out = (float*)d_out;
    float* ws  = (float*)d_ws;   // NBLK*12 floats = 192 KB scratch

    pit_partials<<<dim3(NBLK), dim3(256), 0, stream>>>(preds, targets, ws);
    pit_final<<<dim3(1), dim3(256), 0, stream>>>(ws, out);
}